// Round 2
// baseline (4016.544 us; speedup 1.0000x reference)
//
#include <hip/hip_runtime.h>

// Problem constants
#define B_   16
#define C_   64
#define H_   64
#define W_   64
#define HD_  128
#define O_   640      // 5*HD
#define K_   320      // C + 2*HD
#define SW_  127      // H+W-1

// Decomposition: 8 hd-groups (16 hd each) x 64 col-groups (16 cols each) = 512 blocks
#define NG   8
#define TH   16
#define NCG  64
#define TC   16
#define NT   320      // 5 waves per block
#define SSTR 17       // LDS S-panel stride (bank-spread)
#define GSTR 17       // gate regroup stride (reuses Ss)

// Workspace layout (in floats): state ping-pong first, gathered weights after
#define HB0  0
#define HB1  131072
#define CB0  262144
#define CB1  393216
#define WB   524288            // Wb: 8 * 320 * 80 = 204800 floats
#define WS_END (524288 + 204800)   // 729088 floats = 2.92 MB

__device__ __forceinline__ float sigm(float v) { return 1.f / (1.f + __expf(-v)); }
__device__ __forceinline__ float tanh_fast(float v) {
    float e = __expf(2.f * v);       // saturates cleanly, no NaN at large |v|
    return 1.f - 2.f / (e + 1.f);
}

// ---------------------------------------------------------------------------
// Prep: zero state ping-pong; build Wb[g][k][80] (k-major gathered weights).
// k in [0,64): w_is;  k in [64,192): w_ss[...,1] (h_prev);  k in [192,320): w_ss[...,0] (h_sh)
// local row lr = q*16 + hl  ->  global o = q*128 + g*16 + hl
// All ws writes bounded by n_ws to avoid OOB faults on small workspaces.
// ---------------------------------------------------------------------------
__global__ void lstm_prep(const float* __restrict__ w_is,
                          const float* __restrict__ w_ss,
                          float* __restrict__ ws, int use_wb, long long n_ws)
{
    long long total = use_wb ? (long long)WS_END : (long long)WB;
    if (total > n_ws) total = n_ws;
    const long long stride = (long long)gridDim.x * blockDim.x;
    for (long long idx = (long long)blockIdx.x * blockDim.x + threadIdx.x; idx < total; idx += stride) {
        if (idx < (long long)WB) {
            ws[idx] = 0.f;                       // h/c ping-pong state
        } else {
            int r  = (int)(idx - WB);            // [0, 204800)
            int g  = r / (K_ * 80);
            int rm = r % (K_ * 80);
            int k  = rm / 80;
            int lr = rm % 80;
            int q  = lr >> 4, hl = lr & 15;
            int o  = q * HD_ + g * TH + hl;
            float v;
            if (k < C_)            v = w_is[o * C_ + k];
            else if (k < C_ + HD_) v = w_ss[(o * HD_ + (k - C_)) * 2 + 1];
            else                   v = w_ss[(o * HD_ + (k - C_ - HD_)) * 2 + 0];
            ws[idx] = v;
        }
    }
}

// ---------------------------------------------------------------------------
// One diagonal step j. Block (g, cgp): gate rows {q*128 + g*16 + hl},
// columns n in [cgp*16, cgp*16+16) where n = b*64 + hr.
// State layout: buf[n*128 + hd]. Cross-step visibility via kernel boundary.
// ---------------------------------------------------------------------------
__global__ void __launch_bounds__(NT, 1) lstm_step(
    const float* __restrict__ x,
    const float* __restrict__ Wb,
    const float* __restrict__ w_is,
    const float* __restrict__ w_ss,
    const float* __restrict__ b_is,
    const float* __restrict__ b_ss,
    float* __restrict__ out,
    const float* __restrict__ hc, const float* __restrict__ cc,
    float* __restrict__ hn, float* __restrict__ cn,
    int j, int use_wb)
{
    __shared__ float Ss[K_ * SSTR];   // S-panel [k][col], reused as gate panel [80][col]
    __shared__ float bias_s[80];

    const int tid = threadIdx.x;
    const int g   = blockIdx.x / NCG;
    const int cgp = blockIdx.x % NCG;
    const int n0  = cgp * TC;

    if (tid < 80) {
        int q = tid >> 4, hl = tid & 15;
        int o = q * HD_ + g * TH + hl;
        bias_s[tid] = b_is[o] + b_ss[o];
    }

    // ---- gather S panel into LDS ----
    // x part: k = c in [0,64)
    for (int idx = tid; idx < C_ * TC; idx += NT) {
        int c = idx & 63, col = idx >> 6;
        int n = n0 + col, b = n >> 6, hr = n & 63;
        int w = j - hr;
        float v = 0.f;
        if ((unsigned)w < (unsigned)W_)
            v = x[(((size_t)b * C_ + c) * H_ + hr) * W_ + w];
        Ss[c * SSTR + col] = v;
    }
    // h parts: part 0 -> k = 64+i (h_prev), part 1 -> k = 192+i (h shifted along hr)
    for (int idx = tid; idx < 2 * HD_ * TC; idx += NT) {
        int i    = idx & 127;
        int col  = (idx >> 7) & (TC - 1);
        int part = idx >> 11;
        int n = n0 + col, hr = n & 63;
        float v; int k;
        if (part == 0) { v = hc[(size_t)n * HD_ + i];                  k = C_ + i; }
        else           { v = hr ? hc[(size_t)(n - 1) * HD_ + i] : 0.f; k = C_ + HD_ + i; }
        Ss[k * SSTR + col] = v;
    }
    __syncthreads();

    // ---- GEMM: 80 rows x 16 cols, K=320; W streams from L2, S from LDS ----
    const int rt = tid >> 4;   // 0..19 -> rows 4rt..4rt+3
    const int ct = tid & 15;   // column
    float4 acc = make_float4(0.f, 0.f, 0.f, 0.f);
    const float* sp = Ss + ct;
    if (use_wb) {
        const float* wp = Wb + (size_t)g * (K_ * 80) + 4 * rt;
        #pragma unroll 8
        for (int k = 0; k < K_; ++k) {
            float4 wv = *(const float4*)(wp + (size_t)k * 80);
            float  sv = sp[k * SSTR];
            acc.x += wv.x * sv;
            acc.y += wv.y * sv;
            acc.z += wv.z * sv;
            acc.w += wv.w * sv;
        }
    } else {
        // slow fallback: weights straight from original layout
        int q  = rt >> 2;
        int h0 = (4 * rt) & 15;
        int o0 = q * HD_ + g * TH + h0;        // rows o0..o0+3
        for (int k = 0; k < K_; ++k) {
            float sv = sp[k * SSTR];
            #pragma unroll
            for (int m = 0; m < 4; ++m) {
                int o = o0 + m;
                float wv;
                if (k < C_)            wv = w_is[o * C_ + k];
                else if (k < C_ + HD_) wv = w_ss[(o * HD_ + (k - C_)) * 2 + 1];
                else                   wv = w_ss[(o * HD_ + (k - C_ - HD_)) * 2 + 0];
                ((float*)&acc)[m] += wv * sv;
            }
        }
    }
    __syncthreads();   // all S reads done; safe to overwrite Ss with gates

    Ss[(4 * rt + 0) * GSTR + ct] = acc.x;
    Ss[(4 * rt + 1) * GSTR + ct] = acc.y;
    Ss[(4 * rt + 2) * GSTR + ct] = acc.z;
    Ss[(4 * rt + 3) * GSTR + ct] = acc.w;
    __syncthreads();

    // ---- nonlinearity + state update + streaming output write ----
    if (tid < TH * TC) {
        int hl = tid & 15, col = tid >> 4;
        int n = n0 + col, b = n >> 6, hr = n & 63;
        int hd = g * TH + hl;
        float go  = Ss[(0 * TH + hl) * GSTR + col] + bias_s[0 * TH + hl];
        float gfl = Ss[(1 * TH + hl) * GSTR + col] + bias_s[1 * TH + hl];
        float gfu = Ss[(2 * TH + hl) * GSTR + col] + bias_s[2 * TH + hl];
        float gi  = Ss[(3 * TH + hl) * GSTR + col] + bias_s[3 * TH + hl];
        float gg  = Ss[(4 * TH + hl) * GSTR + col] + bias_s[4 * TH + hl];
        float so = sigm(go), sfl = sigm(gfl), sfu = sigm(gfu), si = sigm(gi);
        float tg = tanh_fast(gg);
        size_t sidx = (size_t)n * HD_ + hd;
        float cp = cc[sidx];
        float cs = hr ? cc[sidx - HD_] : 0.f;
        float cv = sfl * cp + sfu * cs + si * tg;
        float hv = so * tanh_fast(cv);
        cn[sidx] = cv;
        hn[sidx] = hv;
        int w = j - hr;
        if ((unsigned)w < (unsigned)W_)
            out[(((size_t)b * HD_ + hd) * H_ + hr) * W_ + w] = hv;
    }
}

// ---------------------------------------------------------------------------
extern "C" void kernel_launch(void* const* d_in, const int* in_sizes, int n_in,
                              void* d_out, int out_size, void* d_ws, size_t ws_size,
                              hipStream_t stream)
{
    const float* x    = (const float*)d_in[0];
    const float* w_is = (const float*)d_in[1];
    const float* b_is = (const float*)d_in[2];
    const float* w_ss = (const float*)d_in[3];
    const float* b_ss = (const float*)d_in[4];
    float* out = (float*)d_out;
    float* ws  = (float*)d_ws;

    const long long n_ws = (long long)(ws_size / 4);
    const int use_wb = (n_ws >= (long long)WS_END) ? 1 : 0;

    hipLaunchKernelGGL(lstm_prep, dim3(512), dim3(256), 0, stream,
                       w_is, w_ss, ws, use_wb, n_ws);

    const float* Wbp = ws + WB;
    for (int j = 0; j < SW_; ++j) {
        const float* hcp = ws + ((j & 1) ? HB1 : HB0);
        const float* ccp = ws + ((j & 1) ? CB1 : CB0);
        float*       hnp = ws + ((j & 1) ? HB0 : HB1);
        float*       cnp = ws + ((j & 1) ? CB0 : CB1);
        hipLaunchKernelGGL(lstm_step, dim3(NG * NCG), dim3(NT), 0, stream,
                           x, Wbp, w_is, w_ss, b_is, b_ss, out,
                           hcp, ccp, hnp, cnp, j, use_wb);
    }
}